// Round 12
// baseline (22.058 us; speedup 1.0000x reference)
//
#include <hip/hip_runtime.h>
#include <hip/hip_bf16.h>
#include <math.h>

// B=2048, N=16384, D=16
#define BB 2048
#define NN 16384
#define RSA 40                  // A LDS row stride in ushorts (80 B)
#define RSX 32                  // X LDS row stride in ushorts (64 B)
#define NSLICES 128             // 128 slices x 128 n
#define CHUNKS 8
#define MARGIN 60.0f            // gate slack; hi-only bf16 gate err <= ~16
#define LN2 0.6931471805599453f
#define LOG2E 1.4426950408889634f
#define LN2PI 1.8378770664093453f

typedef __attribute__((ext_vector_type(8))) short bf16x8;
typedef __attribute__((ext_vector_type(4))) float f32x4;

__device__ __forceinline__ float EXP2(float v) { return __builtin_amdgcn_exp2f(v); }

__device__ __forceinline__ unsigned pack_bf2(float a, float b) {
    __hip_bfloat162 h = __float22bfloat162_rn(make_float2(a, b));
    union { __hip_bfloat162 h2; unsigned u; } cvt;
    cvt.h2 = h;
    return cvt.u;
}

// ---------------------------------------------------------------------------
// K1: approximate per-(b, slice) max (UNCHANGED from R11 — proven).
// Grid = 128 slices x 16 bgrps, 256 thr. Hi-only bf16 panels, 1 MFMA per
// 16x16 tile, register max over 8 chunks, cross-group merge, 2 stores.
// ---------------------------------------------------------------------------
__global__ __launch_bounds__(256) void kde_max(
    const float* __restrict__ x, const float* __restrict__ mu,
    const float* __restrict__ sigt, const float* __restrict__ wt,
    float* __restrict__ slicemax)
{
    __shared__ ushort AhL[128 * RSA];   // 10 KB
    __shared__ ushort XhL[128 * RSX];   //  8 KB

    const int tid   = threadIdx.x;
    const int slice = blockIdx.x >> 4;
    const int bgrp  = blockIdx.x & 15;

    if (tid < 128) {
        int n = slice * 128 + tid;
        const float4* m4 = (const float4*)(mu + (size_t)n * 16);
        float4 a = m4[0], b = m4[1], c = m4[2], d = m4[3];
        float r[16];
        *(float4*)(r + 0) = a; *(float4*)(r + 4) = b;
        *(float4*)(r + 8) = c; *(float4*)(r + 12) = d;
        float musq = 0.f;
        #pragma unroll
        for (int k = 0; k < 16; ++k) musq = fmaf(r[k], r[k], musq);
        float stv = sigt[n], wv2 = wt[n];
        float A2 = -0.5f * LOG2E * EXP2(-2.0f * LOG2E * stv);
        float C2 = -LOG2E * (16.f * stv + 8.f * LN2PI) + __log2f(wv2);
        unsigned uh[16];
        #pragma unroll
        for (int k = 0; k < 8; ++k)
            uh[k] = pack_bf2(A2 * (-2.f * r[2*k]), A2 * (-2.f * r[2*k+1]));
        uh[8] = pack_bf2(fmaf(A2, musq, C2), A2);
        #pragma unroll
        for (int k = 9; k < 16; ++k) uh[k] = 0u;
        uint4* ph = (uint4*)(AhL + tid * RSA);
        #pragma unroll
        for (int k = 0; k < 4; ++k)
            ph[k] = make_uint4(uh[4*k], uh[4*k+1], uh[4*k+2], uh[4*k+3]);
    } else {
        int b = bgrp * 128 + (tid - 128);
        const float4* x4 = (const float4*)(x + (size_t)b * 16);
        float4 a = x4[0], bb = x4[1], c = x4[2], d = x4[3];
        float r[16];
        *(float4*)(r + 0) = a;  *(float4*)(r + 4) = bb;
        *(float4*)(r + 8) = c;  *(float4*)(r + 12) = d;
        float xsq = 0.f;
        #pragma unroll
        for (int k = 0; k < 16; ++k) xsq = fmaf(r[k], r[k], xsq);
        unsigned uh[16];
        #pragma unroll
        for (int k = 0; k < 8; ++k) uh[k] = pack_bf2(r[2*k], r[2*k+1]);
        uh[8] = pack_bf2(1.0f, xsq);
        #pragma unroll
        for (int k = 9; k < 16; ++k) uh[k] = 0u;
        uint4* ph = (uint4*)(XhL + (tid - 128) * RSX);
        #pragma unroll
        for (int k = 0; k < 4; ++k)
            ph[k] = make_uint4(uh[4*k], uh[4*k+1], uh[4*k+2], uh[4*k+3]);
    }
    __syncthreads();

    const int lane = tid & 63;
    const int wv   = tid >> 6;
    const int l15  = lane & 15, g = lane >> 4;

    bf16x8 bh0 = *(const bf16x8*)(XhL + (wv * 32 + l15) * RSX + g * 8);
    bf16x8 bh1 = *(const bf16x8*)(XhL + (wv * 32 + 16 + l15) * RSX + g * 8);

    float s0 = -INFINITY, s1 = -INFINITY;
    #pragma unroll
    for (int c = 0; c < CHUNKS; ++c) {
        bf16x8 ah = *(const bf16x8*)(AhL + (c * 16 + l15) * RSA + g * 8);
        f32x4 a0 = {0.f, 0.f, 0.f, 0.f};
        a0 = __builtin_amdgcn_mfma_f32_16x16x32_bf16(ah, bh0, a0, 0, 0, 0);
        s0 = fmaxf(s0, fmaxf(fmaxf(a0[0], a0[1]), fmaxf(a0[2], a0[3])));
        f32x4 a1 = {0.f, 0.f, 0.f, 0.f};
        a1 = __builtin_amdgcn_mfma_f32_16x16x32_bf16(ah, bh1, a1, 0, 0, 0);
        s1 = fmaxf(s1, fmaxf(fmaxf(a1[0], a1[1]), fmaxf(a1[2], a1[3])));
    }
    s0 = fmaxf(s0, __shfl_xor(s0, 16, 64));
    s0 = fmaxf(s0, __shfl_xor(s0, 32, 64));
    s1 = fmaxf(s1, __shfl_xor(s1, 16, 64));
    s1 = fmaxf(s1, __shfl_xor(s1, 32, 64));

    if (lane < 16) {
        int b0 = bgrp * 128 + wv * 32 + l15;
        slicemax[(size_t)b0 * NSLICES + slice]        = s0;
        slicemax[(size_t)(b0 + 16) * NSLICES + slice] = s1;
    }
}

// ---------------------------------------------------------------------------
// K2: exact sparse gather, 2 waves per sample. Grid = 1024 blocks x 256 thr.
// Block handles 2 b's; wave pair (half=0,1) each gates one 64-slice half
// (1 coalesced load + butterfly), LDS-exchange -> common M; each wave
// evaluates its own half's surviving slices EXACTLY in fp32 (64 lanes x 2 n,
// coalesced mu rows); partial S -> LDS -> fixed-order combine -> out.
// Deterministic; M cancels in M + log2(sum 2^(e2-M)).
// ---------------------------------------------------------------------------
__global__ __launch_bounds__(256) void kde_gather(
    const float* __restrict__ x, const float* __restrict__ mu,
    const float* __restrict__ sigt, const float* __restrict__ wt,
    const float* __restrict__ slicemax, float* __restrict__ out)
{
    __shared__ float sM[4];
    __shared__ float sS[4];

    const int tid  = threadIdx.x;
    const int lane = tid & 63;
    const int wv   = tid >> 6;      // 0..3
    const int pair = wv >> 1;       // which of the block's 2 samples
    const int half = wv & 1;        // which 64-slice half
    const int b    = blockIdx.x * 2 + pair;

    float xr[16];
    {
        const float4* x4 = (const float4*)(x + (size_t)b * 16);
        float4 a = x4[0], bb = x4[1], c = x4[2], d = x4[3];
        *(float4*)(xr + 0) = a;  *(float4*)(xr + 4) = bb;
        *(float4*)(xr + 8) = c;  *(float4*)(xr + 12) = d;
    }
    float xsq = 0.f;
    #pragma unroll
    for (int k = 0; k < 16; ++k) xsq = fmaf(xr[k], xr[k], xsq);

    // gate load: this wave's half of the slice maxes
    const float v = slicemax[(size_t)b * NSLICES + half * 64 + lane];

    float Mh = v;
    #pragma unroll
    for (int off = 1; off < 64; off <<= 1)
        Mh = fmaxf(Mh, __shfl_xor(Mh, off, 64));
    if (lane == 0) sM[wv] = Mh;
    __syncthreads();
    const float M = fmaxf(sM[pair * 2], sM[pair * 2 + 1]);

    const float gate = M - MARGIN;
    unsigned long long mk = __ballot(v >= gate);

    float S = 0.f;
    while (mk) {
        int bit = __builtin_ctzll(mk);
        mk &= mk - 1;
        int sl = half * 64 + bit;
        #pragma unroll
        for (int h = 0; h < 2; ++h) {
            int n = sl * 128 + h * 64 + lane;
            const float4* m4 = (const float4*)(mu + (size_t)n * 16);
            float4 ma = m4[0], mb = m4[1], mc = m4[2], md = m4[3];
            float mr[16];
            *(float4*)(mr + 0) = ma; *(float4*)(mr + 4) = mb;
            *(float4*)(mr + 8) = mc; *(float4*)(mr + 12) = md;
            float dotv = 0.f, musq = 0.f;
            #pragma unroll
            for (int j = 0; j < 16; ++j) {
                dotv = fmaf(xr[j], mr[j], dotv);
                musq = fmaf(mr[j], mr[j], musq);
            }
            float stv = sigt[n], wv2 = wt[n];
            float A2 = -0.5f * LOG2E * EXP2(-2.0f * LOG2E * stv);
            float C2 = -LOG2E * (16.f * stv + 8.f * LN2PI) + __log2f(wv2);
            float e2 = fmaf(A2, xsq - 2.f * dotv + musq, C2);
            S += EXP2(e2 - M);
        }
    }
    #pragma unroll
    for (int off = 1; off < 64; off <<= 1)
        S += __shfl_xor(S, off, 64);

    if (lane == 0) sS[wv] = S;
    __syncthreads();
    if (half == 0 && lane == 0) {
        float St = sS[pair * 2] + sS[pair * 2 + 1];   // fixed order
        out[b] = (M + __log2f(St)) * LN2;
    }
}

extern "C" void kernel_launch(void* const* d_in, const int* in_sizes, int n_in,
                              void* d_out, int out_size, void* d_ws, size_t ws_size,
                              hipStream_t stream) {
    const float* x  = (const float*)d_in[0];
    const float* mu = (const float*)d_in[1];
    const float* st = (const float*)d_in[2];
    const float* w  = (const float*)d_in[3];
    float* out = (float*)d_out;

    float* slicemax = (float*)d_ws;                 // 2048 * 128 * 4 = 1 MB

    hipLaunchKernelGGL(kde_max, dim3(NSLICES * 16), dim3(256), 0, stream,
                       x, mu, st, w, slicemax);
    hipLaunchKernelGGL(kde_gather, dim3(BB / 2), dim3(256), 0, stream,
                       x, mu, st, w, slicemax, out);
}

// Round 13
// 19.906 us; speedup vs baseline: 1.1081x; 1.1081x over previous
//
#include <hip/hip_runtime.h>
#include <hip/hip_bf16.h>
#include <math.h>

// B=2048, N=16384, D=16
#define BB 2048
#define NN 16384
#define RSA 40                  // A LDS row stride in ushorts (80 B)
#define RSX 32                  // X LDS row stride in ushorts (64 B)
#define NSLICES 128             // 128 slices x 128 n
#define CHUNKS 8
#define MARGIN 60.0f            // gate slack; hi-only bf16 gate err <= ~16
#define LN2 0.6931471805599453f
#define LOG2E 1.4426950408889634f
#define LN2PI 1.8378770664093453f

typedef __attribute__((ext_vector_type(8))) short bf16x8;
typedef __attribute__((ext_vector_type(4))) float f32x4;

__device__ __forceinline__ float EXP2(float v) { return __builtin_amdgcn_exp2f(v); }

__device__ __forceinline__ unsigned pack_bf2(float a, float b) {
    __hip_bfloat162 h = __float22bfloat162_rn(make_float2(a, b));
    union { __hip_bfloat162 h2; unsigned u; } cvt;
    cvt.h2 = h;
    return cvt.u;
}

// ---------------------------------------------------------------------------
// K1: approximate per-(b, slice) max. Grid = 128 slices x 16 bgrps, 256 thr.
// Hi-only bf16 panels (gate precision only: err <= ~16 log2 units), 1 MFMA
// per 16x16 tile, running in-register max over the slice's 8 chunks, one
// cross-group merge, 2 scalar stores per lane<16. No atomics, no exp2.
// Layout slicemax[b][128] -> K2 reads 128 contiguous floats per b.
// ---------------------------------------------------------------------------
__global__ __launch_bounds__(256) void kde_max(
    const float* __restrict__ x, const float* __restrict__ mu,
    const float* __restrict__ sigt, const float* __restrict__ wt,
    float* __restrict__ slicemax)
{
    __shared__ ushort AhL[128 * RSA];   // 10 KB
    __shared__ ushort XhL[128 * RSX];   //  8 KB

    const int tid   = threadIdx.x;
    const int slice = blockIdx.x >> 4;
    const int bgrp  = blockIdx.x & 15;

    // ---------------- prep one augmented row per thread (hi-only) ---------
    if (tid < 128) {
        int n = slice * 128 + tid;
        const float4* m4 = (const float4*)(mu + (size_t)n * 16);
        float4 a = m4[0], b = m4[1], c = m4[2], d = m4[3];
        float r[16];
        *(float4*)(r + 0) = a; *(float4*)(r + 4) = b;
        *(float4*)(r + 8) = c; *(float4*)(r + 12) = d;
        float musq = 0.f;
        #pragma unroll
        for (int k = 0; k < 16; ++k) musq = fmaf(r[k], r[k], musq);
        float stv = sigt[n], wv2 = wt[n];
        float A2 = -0.5f * LOG2E * EXP2(-2.0f * LOG2E * stv);
        float C2 = -LOG2E * (16.f * stv + 8.f * LN2PI) + __log2f(wv2);
        unsigned uh[16];
        #pragma unroll
        for (int k = 0; k < 8; ++k)
            uh[k] = pack_bf2(A2 * (-2.f * r[2*k]), A2 * (-2.f * r[2*k+1]));
        uh[8] = pack_bf2(fmaf(A2, musq, C2), A2);
        #pragma unroll
        for (int k = 9; k < 16; ++k) uh[k] = 0u;
        uint4* ph = (uint4*)(AhL + tid * RSA);
        #pragma unroll
        for (int k = 0; k < 4; ++k)
            ph[k] = make_uint4(uh[4*k], uh[4*k+1], uh[4*k+2], uh[4*k+3]);
    } else {
        int b = bgrp * 128 + (tid - 128);
        const float4* x4 = (const float4*)(x + (size_t)b * 16);
        float4 a = x4[0], bb = x4[1], c = x4[2], d = x4[3];
        float r[16];
        *(float4*)(r + 0) = a;  *(float4*)(r + 4) = bb;
        *(float4*)(r + 8) = c;  *(float4*)(r + 12) = d;
        float xsq = 0.f;
        #pragma unroll
        for (int k = 0; k < 16; ++k) xsq = fmaf(r[k], r[k], xsq);
        unsigned uh[16];
        #pragma unroll
        for (int k = 0; k < 8; ++k) uh[k] = pack_bf2(r[2*k], r[2*k+1]);
        uh[8] = pack_bf2(1.0f, xsq);
        #pragma unroll
        for (int k = 9; k < 16; ++k) uh[k] = 0u;
        uint4* ph = (uint4*)(XhL + (tid - 128) * RSX);
        #pragma unroll
        for (int k = 0; k < 4; ++k)
            ph[k] = make_uint4(uh[4*k], uh[4*k+1], uh[4*k+2], uh[4*k+3]);
    }
    __syncthreads();

    // ---------------- slice max (1 MFMA per tile, register max) -----------
    const int lane = tid & 63;
    const int wv   = tid >> 6;
    const int l15  = lane & 15, g = lane >> 4;

    bf16x8 bh0 = *(const bf16x8*)(XhL + (wv * 32 + l15) * RSX + g * 8);
    bf16x8 bh1 = *(const bf16x8*)(XhL + (wv * 32 + 16 + l15) * RSX + g * 8);

    float s0 = -INFINITY, s1 = -INFINITY;
    #pragma unroll
    for (int c = 0; c < CHUNKS; ++c) {
        bf16x8 ah = *(const bf16x8*)(AhL + (c * 16 + l15) * RSA + g * 8);
        f32x4 a0 = {0.f, 0.f, 0.f, 0.f};
        a0 = __builtin_amdgcn_mfma_f32_16x16x32_bf16(ah, bh0, a0, 0, 0, 0);
        s0 = fmaxf(s0, fmaxf(fmaxf(a0[0], a0[1]), fmaxf(a0[2], a0[3])));
        f32x4 a1 = {0.f, 0.f, 0.f, 0.f};
        a1 = __builtin_amdgcn_mfma_f32_16x16x32_bf16(ah, bh1, a1, 0, 0, 0);
        s1 = fmaxf(s1, fmaxf(fmaxf(a1[0], a1[1]), fmaxf(a1[2], a1[3])));
    }
    s0 = fmaxf(s0, __shfl_xor(s0, 16, 64));
    s0 = fmaxf(s0, __shfl_xor(s0, 32, 64));
    s1 = fmaxf(s1, __shfl_xor(s1, 16, 64));
    s1 = fmaxf(s1, __shfl_xor(s1, 32, 64));

    if (lane < 16) {
        int b0 = bgrp * 128 + wv * 32 + l15;
        slicemax[(size_t)b0 * NSLICES + slice]        = s0;
        slicemax[(size_t)(b0 + 16) * NSLICES + slice] = s1;
    }
}

// ---------------------------------------------------------------------------
// K2: exact sparse gather, slice-gated. One wave per sample b (512 x 256).
// 2 coalesced loads cover the 128 slice maxes; butterfly -> M; 2 ballots ->
// survivor masks; each surviving slice (expect 1-3): 64 lanes x 2 n exact
// fp32 eval (coalesced mu rows), per-lane accumulate; one final butterfly.
// Fixed order -> deterministic. M cancels: out = ln2*(M + log2 sum 2^(e2-M)).
// ---------------------------------------------------------------------------
__global__ __launch_bounds__(256) void kde_gather(
    const float* __restrict__ x, const float* __restrict__ mu,
    const float* __restrict__ sigt, const float* __restrict__ wt,
    const float* __restrict__ slicemax, float* __restrict__ out)
{
    const int tid  = threadIdx.x;
    const int lane = tid & 63;
    const int b    = blockIdx.x * 4 + (tid >> 6);

    float xr[16];
    {
        const float4* x4 = (const float4*)(x + (size_t)b * 16);
        float4 a = x4[0], bb = x4[1], c = x4[2], d = x4[3];
        *(float4*)(xr + 0) = a;  *(float4*)(xr + 4) = bb;
        *(float4*)(xr + 8) = c;  *(float4*)(xr + 12) = d;
    }
    float xsq = 0.f;
    #pragma unroll
    for (int k = 0; k < 16; ++k) xsq = fmaf(xr[k], xr[k], xsq);

    const float v0 = slicemax[(size_t)b * NSLICES + lane];
    const float v1 = slicemax[(size_t)b * NSLICES + 64 + lane];

    float M = fmaxf(v0, v1);
    #pragma unroll
    for (int off = 1; off < 64; off <<= 1)
        M = fmaxf(M, __shfl_xor(M, off, 64));

    const float gate = M - MARGIN;
    unsigned long long m0 = __ballot(v0 >= gate);
    unsigned long long m1 = __ballot(v1 >= gate);

    float S = 0.f;
    #pragma unroll
    for (int half = 0; half < 2; ++half) {
        unsigned long long mk = half ? m1 : m0;
        const int base = half ? 64 : 0;
        while (mk) {
            int bit = __builtin_ctzll(mk);
            mk &= mk - 1;
            int sl = base + bit;
            #pragma unroll
            for (int h = 0; h < 2; ++h) {
                int n = sl * 128 + h * 64 + lane;
                const float4* m4 = (const float4*)(mu + (size_t)n * 16);
                float4 ma = m4[0], mb = m4[1], mc = m4[2], md = m4[3];
                float mr[16];
                *(float4*)(mr + 0) = ma; *(float4*)(mr + 4) = mb;
                *(float4*)(mr + 8) = mc; *(float4*)(mr + 12) = md;
                float dotv = 0.f, musq = 0.f;
                #pragma unroll
                for (int j = 0; j < 16; ++j) {
                    dotv = fmaf(xr[j], mr[j], dotv);
                    musq = fmaf(mr[j], mr[j], musq);
                }
                float stv = sigt[n], wv2 = wt[n];
                float A2 = -0.5f * LOG2E * EXP2(-2.0f * LOG2E * stv);
                float C2 = -LOG2E * (16.f * stv + 8.f * LN2PI) + __log2f(wv2);
                float e2 = fmaf(A2, xsq - 2.f * dotv + musq, C2);
                S += EXP2(e2 - M);
            }
        }
    }
    #pragma unroll
    for (int off = 1; off < 64; off <<= 1)
        S += __shfl_xor(S, off, 64);

    if (lane == 0) out[b] = (M + __log2f(S)) * LN2;
}

extern "C" void kernel_launch(void* const* d_in, const int* in_sizes, int n_in,
                              void* d_out, int out_size, void* d_ws, size_t ws_size,
                              hipStream_t stream) {
    const float* x  = (const float*)d_in[0];
    const float* mu = (const float*)d_in[1];
    const float* st = (const float*)d_in[2];
    const float* w  = (const float*)d_in[3];
    float* out = (float*)d_out;

    float* slicemax = (float*)d_ws;                 // 2048 * 128 * 4 = 1 MB

    hipLaunchKernelGGL(kde_max, dim3(NSLICES * 16), dim3(256), 0, stream,
                       x, mu, st, w, slicemax);
    hipLaunchKernelGGL(kde_gather, dim3(BB / 4), dim3(256), 0, stream,
                       x, mu, st, w, slicemax, out);
}